// Round 5
// baseline (310.797 us; speedup 1.0000x reference)
//
#include <hip/hip_runtime.h>

#define C_DIM 64
#define B_DIM 4

typedef unsigned short u16;
typedef unsigned int u32;

__device__ __forceinline__ float bf2f(u16 v) {
    union { u32 u; float f; } t; t.u = ((u32)v) << 16; return t.f;
}
__device__ __forceinline__ u16 f2bf(float f) {
    union { u32 u; float f; } t; t.f = f;
    u32 u = t.u;
    return (u16)((u + 0x7FFF + ((u >> 16) & 1)) >> 16);  // RNE
}
__device__ __forceinline__ float lo16(u32 u) {
    union { u32 v; float f; } t; t.v = u << 16; return t.f;
}
__device__ __forceinline__ float hi16(u32 u) {
    union { u32 v; float f; } t; t.v = u & 0xffff0000u; return t.f;
}

// ---- fused: fp32 (B,N,C) -> bf16 (N,B*C) transpose+convert  AND  dst histogram ----
__global__ __launch_bounds__(256) void k_pre(
    const float* __restrict__ in, u16* __restrict__ outb, int n_nodes,
    const int* __restrict__ dst, int* __restrict__ counts, int n_edges,
    int cvt_blocks)
{
    if ((int)blockIdx.x < cvt_blocks) {
        int i = blockIdx.x * 256 + threadIdx.x;      // [0, n_nodes*32)
        if (i >= n_nodes * 32) return;
        int n = i >> 5;
        int r = i & 31;
        int b = r >> 3, c8 = (r & 7) << 3;
        const float4* p = (const float4*)(in + ((size_t)b * n_nodes + n) * 64 + c8);
        float4 A = p[0], B = p[1];
        ushort4 lo, hi;
        lo.x = f2bf(A.x); lo.y = f2bf(A.y); lo.z = f2bf(A.z); lo.w = f2bf(A.w);
        hi.x = f2bf(B.x); hi.y = f2bf(B.y); hi.z = f2bf(B.z); hi.w = f2bf(B.w);
        ushort4* q = (ushort4*)(outb + (size_t)n * 256 + b * 64 + c8);
        q[0] = lo; q[1] = hi;
    } else {
        int e = (blockIdx.x - cvt_blocks) * 256 + threadIdx.x;
        if (e < n_edges) atomicAdd(&counts[dst[e]], 1);
    }
}

// ---------------- CSR build ----------------

__global__ __launch_bounds__(256) void k_part(
    const int* __restrict__ counts, int* __restrict__ partials, int n_nodes)
{
    __shared__ int s[256];
    int i = blockIdx.x * 256 + threadIdx.x;
    int v = (i < n_nodes) ? counts[i] : 0;
    s[threadIdx.x] = v;
    __syncthreads();
    for (int d = 128; d > 0; d >>= 1) {
        if (threadIdx.x < d) s[threadIdx.x] += s[threadIdx.x + d];
        __syncthreads();
    }
    if (threadIdx.x == 0) partials[blockIdx.x] = s[0];
}

__global__ __launch_bounds__(256) void k_scan1(
    int* __restrict__ partials, int nb)
{
    __shared__ int s[256];
    int tid = threadIdx.x;
    int v = (tid < nb) ? partials[tid] : 0;
    s[tid] = v;
    __syncthreads();
    for (int d = 1; d < 256; d <<= 1) {
        int t = (tid >= d) ? s[tid - d] : 0;
        __syncthreads();
        s[tid] += t;
        __syncthreads();
    }
    if (tid < nb) partials[tid] = s[tid] - v;   // exclusive
}

__global__ __launch_bounds__(256) void k_final(
    const int* __restrict__ counts, const int* __restrict__ partials,
    int* __restrict__ offsets, int* __restrict__ cursor, int n_nodes)
{
    __shared__ int s[256];
    int tid = threadIdx.x;
    int i = blockIdx.x * 256 + tid;
    int v = (i < n_nodes) ? counts[i] : 0;
    s[tid] = v;
    __syncthreads();
    for (int d = 1; d < 256; d <<= 1) {
        int t = (tid >= d) ? s[tid - d] : 0;
        __syncthreads();
        s[tid] += t;
        __syncthreads();
    }
    if (i < n_nodes) {
        int off = partials[blockIdx.x] + s[tid] - v;
        offsets[i] = off;
        cursor[i] = off;
    }
}

__global__ __launch_bounds__(256) void k_fill(
    const int* __restrict__ src, const int* __restrict__ dst,
    int* __restrict__ cursor, u16* __restrict__ elist, int n_edges)
{
    int e = blockIdx.x * 256 + threadIdx.x;
    if (e < n_edges) {
        int pos = atomicAdd(&cursor[dst[e]], 1);
        elist[pos] = (u16)src[e];
    }
}

// ---- gather(+self) over all batches: one wave per node, no LDS, no barriers ----
// hb/aggb layout: (N, B*C) bf16. Lane l owns 8B (4 bf16) at col l*4.
__global__ __launch_bounds__(256) void k_gather(
    const u16* __restrict__ hb, const u16* __restrict__ elist,
    const int* __restrict__ offsets, u16* __restrict__ aggb,
    int n_nodes, int n_edges)
{
    int gw = (blockIdx.x * 256 + threadIdx.x) >> 6;
    int nw = (gridDim.x * 256) >> 6;
    int l = threadIdx.x & 63;
    const u16* px = hb + (l << 2);

    for (int node = gw; node < n_nodes; node += nw) {
        int ks = offsets[node];
        int ke = (node + 1 < n_nodes) ? offsets[node + 1] : n_edges;
        uint2 sv = *(const uint2*)(px + ((size_t)node << 8));   // self
        float a0 = lo16(sv.x), a1 = hi16(sv.x), a2 = lo16(sv.y), a3 = hi16(sv.y);
        int k = ks;
        for (; k + 8 <= ke; k += 8) {
            int s0 = elist[k + 0], s1 = elist[k + 1], s2 = elist[k + 2], s3 = elist[k + 3];
            int s4 = elist[k + 4], s5 = elist[k + 5], s6 = elist[k + 6], s7 = elist[k + 7];
            uint2 v0 = *(const uint2*)(px + ((size_t)s0 << 8));
            uint2 v1 = *(const uint2*)(px + ((size_t)s1 << 8));
            uint2 v2 = *(const uint2*)(px + ((size_t)s2 << 8));
            uint2 v3 = *(const uint2*)(px + ((size_t)s3 << 8));
            uint2 v4 = *(const uint2*)(px + ((size_t)s4 << 8));
            uint2 v5 = *(const uint2*)(px + ((size_t)s5 << 8));
            uint2 v6 = *(const uint2*)(px + ((size_t)s6 << 8));
            uint2 v7 = *(const uint2*)(px + ((size_t)s7 << 8));
            a0 += lo16(v0.x); a1 += hi16(v0.x); a2 += lo16(v0.y); a3 += hi16(v0.y);
            a0 += lo16(v1.x); a1 += hi16(v1.x); a2 += lo16(v1.y); a3 += hi16(v1.y);
            a0 += lo16(v2.x); a1 += hi16(v2.x); a2 += lo16(v2.y); a3 += hi16(v2.y);
            a0 += lo16(v3.x); a1 += hi16(v3.x); a2 += lo16(v3.y); a3 += hi16(v3.y);
            a0 += lo16(v4.x); a1 += hi16(v4.x); a2 += lo16(v4.y); a3 += hi16(v4.y);
            a0 += lo16(v5.x); a1 += hi16(v5.x); a2 += lo16(v5.y); a3 += hi16(v5.y);
            a0 += lo16(v6.x); a1 += hi16(v6.x); a2 += lo16(v6.y); a3 += hi16(v6.y);
            a0 += lo16(v7.x); a1 += hi16(v7.x); a2 += lo16(v7.y); a3 += hi16(v7.y);
        }
        for (; k < ke; ++k) {
            uint2 v = *(const uint2*)(px + ((size_t)elist[k] << 8));
            a0 += lo16(v.x); a1 += hi16(v.x); a2 += lo16(v.y); a3 += hi16(v.y);
        }
        uint2 o;
        o.x = (u32)f2bf(a0) | ((u32)f2bf(a1) << 16);
        o.y = (u32)f2bf(a2) | ((u32)f2bf(a3) << 16);
        *(uint2*)(aggb + ((size_t)node << 8) + (l << 2)) = o;
    }
}

// ---- streaming 64x64 matmul: out = agg @ W^T + b ----
// block = 4 nodes/iter; thread (w = tid>>6, c = tid&63) computes 4 batch outputs.
__global__ __launch_bounds__(256) void k_mm(
    const u16* __restrict__ aggb,      // (N, B*C) bf16
    const float* __restrict__ W,       // (64,64) row-major (out,in)
    const float* __restrict__ bias,
    float* __restrict__ out_f32,       // (B,N,C) fp32, nullable
    u16* __restrict__ out_bf,          // (N,B*C) bf16, nullable
    int n_nodes)
{
    __shared__ float Ws[64][65];
    __shared__ float rows[2][4][4][64];   // [buf][node-slot][batch][ch]
    int tid = threadIdx.x;
    for (int i = tid; i < 64 * 64; i += 256)
        Ws[i >> 6][i & 63] = W[i];

    int w = tid >> 6;
    int l = tid & 63;
    int bl = l >> 4;
    int cq = (l & 15) << 2;
    float bia = bias[l];
    int step = gridDim.x * 4;

    int node = blockIdx.x * 4 + w;
    uint2 v = make_uint2(0u, 0u);
    if (node < n_nodes)
        v = *(const uint2*)(aggb + ((size_t)node << 8) + (l << 2));

    int p = 0;
    for (int node0 = blockIdx.x * 4; node0 < n_nodes; node0 += step, p ^= 1) {
        node = node0 + w;
        *(float4*)&rows[p][w][bl][cq] =
            make_float4(lo16(v.x), hi16(v.x), lo16(v.y), hi16(v.y));
        // prefetch next group
        int nnode = node + step;
        if (nnode < n_nodes)
            v = *(const uint2*)(aggb + ((size_t)nnode << 8) + (l << 2));
        __syncthreads();
        if (node < n_nodes) {
            float o0 = bia, o1 = bia, o2 = bia, o3 = bia;
#pragma unroll
            for (int k4 = 0; k4 < 64; k4 += 4) {
                float4 r0 = *(const float4*)&rows[p][w][0][k4];
                float4 r1 = *(const float4*)&rows[p][w][1][k4];
                float4 r2 = *(const float4*)&rows[p][w][2][k4];
                float4 r3 = *(const float4*)&rows[p][w][3][k4];
                float w0 = Ws[l][k4 + 0], w1 = Ws[l][k4 + 1];
                float w2 = Ws[l][k4 + 2], w3 = Ws[l][k4 + 3];
                o0 += r0.x * w0 + r0.y * w1 + r0.z * w2 + r0.w * w3;
                o1 += r1.x * w0 + r1.y * w1 + r1.z * w2 + r1.w * w3;
                o2 += r2.x * w0 + r2.y * w1 + r2.z * w2 + r2.w * w3;
                o3 += r3.x * w0 + r3.y * w1 + r3.z * w2 + r3.w * w3;
            }
            if (out_bf) {
                size_t ob = (size_t)node << 8;
                out_bf[ob + 0 * 64 + l] = f2bf(o0);
                out_bf[ob + 1 * 64 + l] = f2bf(o1);
                out_bf[ob + 2 * 64 + l] = f2bf(o2);
                out_bf[ob + 3 * 64 + l] = f2bf(o3);
            }
            if (out_f32) {
                out_f32[(((size_t)0 * n_nodes + node) << 6) + l] = o0;
                out_f32[(((size_t)1 * n_nodes + node) << 6) + l] = o1;
                out_f32[(((size_t)2 * n_nodes + node) << 6) + l] = o2;
                out_f32[(((size_t)3 * n_nodes + node) << 6) + l] = o3;
            }
        }
    }
}

// ---------------- fallback (atomic path, proven) ----------------

__global__ __launch_bounds__(256) void gin_scatter(
    const float* __restrict__ h, const int* __restrict__ src,
    const int* __restrict__ dst, float* __restrict__ agg,
    int n_edges, int n_nodes)
{
    long long i = (long long)blockIdx.x * blockDim.x + threadIdx.x;
    int e = (int)(i >> 6);
    if (e >= n_edges) return;
    int lane = (int)(i & 63);
    int b  = lane >> 4;
    int c4 = (lane & 15) << 2;
    int s = src[e];
    int d = dst[e];
    const float4 v = *reinterpret_cast<const float4*>(
        h + ((size_t)b * n_nodes + s) * C_DIM + c4);
    float* o = agg + ((size_t)b * n_nodes + d) * C_DIM + c4;
    unsafeAtomicAdd(o + 0, v.x);
    unsafeAtomicAdd(o + 1, v.y);
    unsafeAtomicAdd(o + 2, v.z);
    unsafeAtomicAdd(o + 3, v.w);
}

__global__ __launch_bounds__(256) void gin_mm(
    const float* __restrict__ hin, const float* __restrict__ agg,
    const float* __restrict__ W, const float* __restrict__ bias,
    float* __restrict__ out, int M)
{
    __shared__ float Ws[64][65];
    __shared__ float rows[4][64];
    int tid = threadIdx.x;
    for (int i = tid; i < 64 * 64; i += 256)
        Ws[i >> 6][i & 63] = W[i];
    int rloc = tid >> 6;
    int j    = tid & 63;
    int row  = blockIdx.x * 4 + rloc;
    if (row < M)
        rows[rloc][j] = hin[(size_t)row * C_DIM + j] + agg[(size_t)row * C_DIM + j];
    __syncthreads();
    if (row < M) {
        float acc = bias[j];
#pragma unroll
        for (int k = 0; k < 64; ++k)
            acc += rows[rloc][k] * Ws[j][k];
        out[(size_t)row * C_DIM + j] = acc;
    }
}

// ---------------- launch ----------------

static inline size_t align256(size_t x) { return (x + 255) & ~(size_t)255; }

extern "C" void kernel_launch(void* const* d_in, const int* in_sizes, int n_in,
                              void* d_out, int out_size, void* d_ws, size_t ws_size,
                              hipStream_t stream)
{
    const float* x   = (const float*)d_in[0];
    const int*   ei  = (const int*)d_in[1];
    const float* W1  = (const float*)d_in[2];
    const float* b1  = (const float*)d_in[3];
    const float* W2  = (const float*)d_in[4];
    const float* b2  = (const float*)d_in[5];
    float* out = (float*)d_out;

    const int n_nodes = in_sizes[0] / (B_DIM * C_DIM);
    const int n_edges = in_sizes[1] / 2;
    const int M = B_DIM * n_nodes;
    const size_t elems = (size_t)M * C_DIM;

    const int* src = ei;
    const int* dst = ei + n_edges;
    const int NB = (n_nodes + 255) / 256;

    // ws layout (fast path): bufA (x_bf16 / h1_bf16), bufB (agg), CSR arrays
    size_t off = 0;
    size_t o_bufA    = off; off = align256(off + elems * sizeof(u16));
    size_t o_bufB    = off; off = align256(off + elems * sizeof(u16));
    size_t o_counts  = off; off = align256(off + (size_t)n_nodes * sizeof(int));
    size_t o_offsets = off; off = align256(off + (size_t)n_nodes * sizeof(int));
    size_t o_cursor  = off; off = align256(off + (size_t)n_nodes * sizeof(int));
    size_t o_part    = off; off = align256(off + 256 * sizeof(int));
    size_t o_elist   = off; off = align256(off + (size_t)n_edges * sizeof(u16));
    const size_t need = off;

    const bool fast = (ws_size >= need) && (n_nodes <= 65535) && (NB <= 256) &&
                      ((elems & 7) == 0);

    dim3 blk(256);

    if (fast) {
        char* ws = (char*)d_ws;
        u16* bufA    = (u16*)(ws + o_bufA);
        u16* bufB    = (u16*)(ws + o_bufB);
        int* counts  = (int*)(ws + o_counts);
        int* offsets = (int*)(ws + o_offsets);
        int* cursor  = (int*)(ws + o_cursor);
        int* partials= (int*)(ws + o_part);
        u16* elist   = (u16*)(ws + o_elist);

        const int cvt_blocks  = (n_nodes * 32 + 255) / 256;
        const int hist_blocks = (n_edges + 255) / 256;
        dim3 grid_pre((unsigned)(cvt_blocks + hist_blocks));
        dim3 grid_e((unsigned)hist_blocks);
        dim3 grid_n((unsigned)NB);
        dim3 grid_g(2048);
        dim3 grid_m(2048);

        hipMemsetAsync(counts, 0, (size_t)n_nodes * sizeof(int), stream);
        k_pre<<<grid_pre, blk, 0, stream>>>(x, bufA, n_nodes, dst, counts,
                                            n_edges, cvt_blocks);
        k_part<<<grid_n, blk, 0, stream>>>(counts, partials, n_nodes);
        k_scan1<<<1, blk, 0, stream>>>(partials, NB);
        k_final<<<grid_n, blk, 0, stream>>>(counts, partials, offsets, cursor, n_nodes);
        k_fill<<<grid_e, blk, 0, stream>>>(src, dst, cursor, elist, n_edges);

        // layer 1
        k_gather<<<grid_g, blk, 0, stream>>>(bufA, elist, offsets, bufB,
                                             n_nodes, n_edges);
        k_mm<<<grid_m, blk, 0, stream>>>(bufB, W1, b1, nullptr, bufA, n_nodes);
        // layer 2
        k_gather<<<grid_g, blk, 0, stream>>>(bufA, elist, offsets, bufB,
                                             n_nodes, n_edges);
        k_mm<<<grid_m, blk, 0, stream>>>(bufB, W2, b2, out, nullptr, n_nodes);
    } else {
        // fallback: atomic path
        float* agg = (float*)d_ws;
        const size_t h_bytes = elems * sizeof(float);
        dim3 grid_sc((unsigned)(((long long)n_edges * 64 + 255) / 256));
        dim3 grid_mm((unsigned)((M + 3) / 4));

        hipMemsetAsync(agg, 0, h_bytes, stream);
        gin_scatter<<<grid_sc, blk, 0, stream>>>(x, src, dst, agg, n_edges, n_nodes);
        gin_mm<<<grid_mm, blk, 0, stream>>>(x, agg, W1, b1, out, M);

        hipMemsetAsync(agg, 0, h_bytes, stream);
        gin_scatter<<<grid_sc, blk, 0, stream>>>(out, src, dst, agg, n_edges, n_nodes);
        gin_mm<<<grid_mm, blk, 0, stream>>>(out, agg, W2, b2, out, M);
    }
}

// Round 6
// 271.657 us; speedup vs baseline: 1.1441x; 1.1441x over previous
//
#include <hip/hip_runtime.h>

#define C_DIM 64
#define B_DIM 4

typedef unsigned short u16;
typedef unsigned int u32;
typedef __attribute__((ext_vector_type(8))) short s16x8;
typedef __attribute__((ext_vector_type(4))) float f32x4;

__device__ __forceinline__ float bf2f(u16 v) {
    union { u32 u; float f; } t; t.u = ((u32)v) << 16; return t.f;
}
__device__ __forceinline__ u16 f2bf(float f) {
    union { u32 u; float f; } t; t.f = f;
    u32 u = t.u;
    return (u16)((u + 0x7FFF + ((u >> 16) & 1)) >> 16);  // RNE
}
__device__ __forceinline__ float lo16(u32 u) {
    union { u32 v; float f; } t; t.v = u << 16; return t.f;
}
__device__ __forceinline__ float hi16(u32 u) {
    union { u32 v; float f; } t; t.v = u & 0xffff0000u; return t.f;
}

// ---- fused: fp32 (B,N,C) -> bf16 (N,B*C) transpose+convert  AND  dst histogram ----
__global__ __launch_bounds__(256) void k_pre(
    const float* __restrict__ in, u16* __restrict__ outb, int n_nodes,
    const int* __restrict__ dst, int* __restrict__ counts, int n_edges,
    int cvt_blocks)
{
    if ((int)blockIdx.x < cvt_blocks) {
        int i = blockIdx.x * 256 + threadIdx.x;      // [0, n_nodes*32)
        if (i >= n_nodes * 32) return;
        int n = i >> 5;
        int r = i & 31;
        int b = r >> 3, c8 = (r & 7) << 3;
        const float4* p = (const float4*)(in + ((size_t)b * n_nodes + n) * 64 + c8);
        float4 A = p[0], B = p[1];
        ushort4 lo, hi;
        lo.x = f2bf(A.x); lo.y = f2bf(A.y); lo.z = f2bf(A.z); lo.w = f2bf(A.w);
        hi.x = f2bf(B.x); hi.y = f2bf(B.y); hi.z = f2bf(B.z); hi.w = f2bf(B.w);
        ushort4* q = (ushort4*)(outb + (size_t)n * 256 + b * 64 + c8);
        q[0] = lo; q[1] = hi;
    } else {
        int e = (blockIdx.x - cvt_blocks) * 256 + threadIdx.x;
        if (e < n_edges) atomicAdd(&counts[dst[e]], 1);
    }
}

// ---------------- CSR build ----------------

__global__ __launch_bounds__(256) void k_part(
    const int* __restrict__ counts, int* __restrict__ partials, int n_nodes)
{
    __shared__ int s[256];
    int i = blockIdx.x * 256 + threadIdx.x;
    int v = (i < n_nodes) ? counts[i] : 0;
    s[threadIdx.x] = v;
    __syncthreads();
    for (int d = 128; d > 0; d >>= 1) {
        if (threadIdx.x < d) s[threadIdx.x] += s[threadIdx.x + d];
        __syncthreads();
    }
    if (threadIdx.x == 0) partials[blockIdx.x] = s[0];
}

__global__ __launch_bounds__(256) void k_scan1(
    int* __restrict__ partials, int nb)
{
    __shared__ int s[256];
    int tid = threadIdx.x;
    int v = (tid < nb) ? partials[tid] : 0;
    s[tid] = v;
    __syncthreads();
    for (int d = 1; d < 256; d <<= 1) {
        int t = (tid >= d) ? s[tid - d] : 0;
        __syncthreads();
        s[tid] += t;
        __syncthreads();
    }
    if (tid < nb) partials[tid] = s[tid] - v;   // exclusive
}

__global__ __launch_bounds__(256) void k_final(
    const int* __restrict__ counts, const int* __restrict__ partials,
    int* __restrict__ offsets, int* __restrict__ cursor, int n_nodes)
{
    __shared__ int s[256];
    int tid = threadIdx.x;
    int i = blockIdx.x * 256 + tid;
    int v = (i < n_nodes) ? counts[i] : 0;
    s[tid] = v;
    __syncthreads();
    for (int d = 1; d < 256; d <<= 1) {
        int t = (tid >= d) ? s[tid - d] : 0;
        __syncthreads();
        s[tid] += t;
        __syncthreads();
    }
    if (i < n_nodes) {
        int off = partials[blockIdx.x] + s[tid] - v;
        offsets[i] = off;
        cursor[i] = off;
    }
}

__global__ __launch_bounds__(256) void k_fill(
    const int* __restrict__ src, const int* __restrict__ dst,
    int* __restrict__ cursor, u16* __restrict__ elist, int n_edges)
{
    int e = blockIdx.x * 256 + threadIdx.x;
    if (e < n_edges) {
        int pos = atomicAdd(&cursor[dst[e]], 1);
        elist[pos] = (u16)src[e];
    }
}

// ---- gather(+self) over all batches: one wave per node, no LDS, no barriers ----
// hb/aggb layout: (N, B*C) bf16. Lane l owns 8B (4 bf16) at col l*4.
__global__ __launch_bounds__(256) void k_gather(
    const u16* __restrict__ hb, const u16* __restrict__ elist,
    const int* __restrict__ offsets, u16* __restrict__ aggb,
    int n_nodes, int n_edges)
{
    int gw = __builtin_amdgcn_readfirstlane((blockIdx.x * 256 + threadIdx.x) >> 6);
    int nw = (gridDim.x * 256) >> 6;
    int l = threadIdx.x & 63;
    const u16* px = hb + (l << 2);

    for (int node = gw; node < n_nodes; node += nw) {
        int ks = __builtin_amdgcn_readfirstlane(offsets[node]);
        int ke = __builtin_amdgcn_readfirstlane(
            (node + 1 < n_nodes) ? offsets[node + 1] : n_edges);
        uint2 sv = *(const uint2*)(px + ((size_t)node << 8));   // self
        float a0 = lo16(sv.x), a1 = hi16(sv.x), a2 = lo16(sv.y), a3 = hi16(sv.y);
        int k = ks;
        for (; k + 8 <= ke; k += 8) {
            int s0 = elist[k + 0], s1 = elist[k + 1], s2 = elist[k + 2], s3 = elist[k + 3];
            int s4 = elist[k + 4], s5 = elist[k + 5], s6 = elist[k + 6], s7 = elist[k + 7];
            uint2 v0 = *(const uint2*)(px + ((size_t)s0 << 8));
            uint2 v1 = *(const uint2*)(px + ((size_t)s1 << 8));
            uint2 v2 = *(const uint2*)(px + ((size_t)s2 << 8));
            uint2 v3 = *(const uint2*)(px + ((size_t)s3 << 8));
            uint2 v4 = *(const uint2*)(px + ((size_t)s4 << 8));
            uint2 v5 = *(const uint2*)(px + ((size_t)s5 << 8));
            uint2 v6 = *(const uint2*)(px + ((size_t)s6 << 8));
            uint2 v7 = *(const uint2*)(px + ((size_t)s7 << 8));
            a0 += lo16(v0.x); a1 += hi16(v0.x); a2 += lo16(v0.y); a3 += hi16(v0.y);
            a0 += lo16(v1.x); a1 += hi16(v1.x); a2 += lo16(v1.y); a3 += hi16(v1.y);
            a0 += lo16(v2.x); a1 += hi16(v2.x); a2 += lo16(v2.y); a3 += hi16(v2.y);
            a0 += lo16(v3.x); a1 += hi16(v3.x); a2 += lo16(v3.y); a3 += hi16(v3.y);
            a0 += lo16(v4.x); a1 += hi16(v4.x); a2 += lo16(v4.y); a3 += hi16(v4.y);
            a0 += lo16(v5.x); a1 += hi16(v5.x); a2 += lo16(v5.y); a3 += hi16(v5.y);
            a0 += lo16(v6.x); a1 += hi16(v6.x); a2 += lo16(v6.y); a3 += hi16(v6.y);
            a0 += lo16(v7.x); a1 += hi16(v7.x); a2 += lo16(v7.y); a3 += hi16(v7.y);
        }
        for (; k < ke; ++k) {
            uint2 v = *(const uint2*)(px + ((size_t)elist[k] << 8));
            a0 += lo16(v.x); a1 += hi16(v.x); a2 += lo16(v.y); a3 += hi16(v.y);
        }
        uint2 o;
        o.x = (u32)f2bf(a0) | ((u32)f2bf(a1) << 16);
        o.y = (u32)f2bf(a2) | ((u32)f2bf(a3) << 16);
        *(uint2*)(aggb + ((size_t)node << 8) + (l << 2)) = o;
    }
}

// ---- MFMA matmul: D(R=4N, 64) = A(R,64) @ W^T + bias, A bf16 row-major ----
// (N,B*C) layout == row-major (4N,64) since n*256 + b*64 = (4n+b)*64.
// One wave per 16-row tile; W held entirely in registers as 8 B-frags.
// mfma_f32_16x16x32_bf16: A lane: row=l&15, k=(l>>4)*8+e; B lane: col=l&15,
// k=(l>>4)*8+e; D lane: col=l&15, row=(l>>4)*4+reg (guide §3, m89-verified).
__global__ __launch_bounds__(256) void k_mm_mfma(
    const u16* __restrict__ aggb,      // (4N, 64) bf16
    const float* __restrict__ W,       // (64,64) f32 row-major (out,in)
    const float* __restrict__ bias,
    float* __restrict__ out_f32,       // (B,N,C) fp32, nullable
    u16* __restrict__ out_bf,          // (4N,64) bf16, nullable
    int n_nodes)
{
    const int R = n_nodes * 4;
    int l = threadIdx.x & 63;
    int wid = (blockIdx.x * 256 + threadIdx.x) >> 6;
    int nwaves = (gridDim.x * 256) >> 6;
    int lr = l & 15;
    int lk = l >> 4;

    // B fragments: 4 j-tiles x 2 k-slabs; lane needs W[t*16+lr][s*32+lk*8 ..+8]
    s16x8 bfrag[4][2];
#pragma unroll
    for (int t = 0; t < 4; ++t)
#pragma unroll
        for (int s = 0; s < 2; ++s) {
            const float* wp = W + (t * 16 + lr) * 64 + s * 32 + lk * 8;
            s16x8 f;
#pragma unroll
            for (int e = 0; e < 8; ++e) f[e] = (short)f2bf(wp[e]);
            bfrag[t][s] = f;
        }
    float bia[4];
#pragma unroll
    for (int t = 0; t < 4; ++t) bia[t] = bias[t * 16 + lr];

    for (int tile = wid; tile * 16 < R; tile += nwaves) {
        int row0 = tile * 16;
        const u16* ap = aggb + (size_t)(row0 + lr) * 64 + lk * 8;
        s16x8 a0 = *(const s16x8*)(ap);
        s16x8 a1 = *(const s16x8*)(ap + 32);
        f32x4 acc[4];
#pragma unroll
        for (int t = 0; t < 4; ++t)
            acc[t] = (f32x4){bia[t], bia[t], bia[t], bia[t]};
#pragma unroll
        for (int t = 0; t < 4; ++t) {
            acc[t] = __builtin_amdgcn_mfma_f32_16x16x32_bf16(a0, bfrag[t][0], acc[t], 0, 0, 0);
            acc[t] = __builtin_amdgcn_mfma_f32_16x16x32_bf16(a1, bfrag[t][1], acc[t], 0, 0, 0);
        }
        if (out_bf) {
#pragma unroll
            for (int t = 0; t < 4; ++t)
#pragma unroll
                for (int reg = 0; reg < 4; ++reg) {
                    int r = row0 + lk * 4 + reg;
                    out_bf[(size_t)r * 64 + t * 16 + lr] = f2bf(acc[t][reg]);
                }
        }
        if (out_f32) {
#pragma unroll
            for (int t = 0; t < 4; ++t)
#pragma unroll
                for (int reg = 0; reg < 4; ++reg) {
                    int r = row0 + lk * 4 + reg;
                    int n = r >> 2, b = r & 3;
                    out_f32[(((size_t)b * n_nodes + n) << 6) + t * 16 + lr] = acc[t][reg];
                }
        }
    }
}

// ---------------- fallback (atomic path, proven) ----------------

__global__ __launch_bounds__(256) void gin_scatter(
    const float* __restrict__ h, const int* __restrict__ src,
    const int* __restrict__ dst, float* __restrict__ agg,
    int n_edges, int n_nodes)
{
    long long i = (long long)blockIdx.x * blockDim.x + threadIdx.x;
    int e = (int)(i >> 6);
    if (e >= n_edges) return;
    int lane = (int)(i & 63);
    int b  = lane >> 4;
    int c4 = (lane & 15) << 2;
    int s = src[e];
    int d = dst[e];
    const float4 v = *reinterpret_cast<const float4*>(
        h + ((size_t)b * n_nodes + s) * C_DIM + c4);
    float* o = agg + ((size_t)b * n_nodes + d) * C_DIM + c4;
    unsafeAtomicAdd(o + 0, v.x);
    unsafeAtomicAdd(o + 1, v.y);
    unsafeAtomicAdd(o + 2, v.z);
    unsafeAtomicAdd(o + 3, v.w);
}

__global__ __launch_bounds__(256) void gin_mm(
    const float* __restrict__ hin, const float* __restrict__ agg,
    const float* __restrict__ W, const float* __restrict__ bias,
    float* __restrict__ out, int M)
{
    __shared__ float Ws[64][65];
    __shared__ float rows[4][64];
    int tid = threadIdx.x;
    for (int i = tid; i < 64 * 64; i += 256)
        Ws[i >> 6][i & 63] = W[i];
    int rloc = tid >> 6;
    int j    = tid & 63;
    int row  = blockIdx.x * 4 + rloc;
    if (row < M)
        rows[rloc][j] = hin[(size_t)row * C_DIM + j] + agg[(size_t)row * C_DIM + j];
    __syncthreads();
    if (row < M) {
        float acc = bias[j];
#pragma unroll
        for (int k = 0; k < 64; ++k)
            acc += rows[rloc][k] * Ws[j][k];
        out[(size_t)row * C_DIM + j] = acc;
    }
}

// ---------------- launch ----------------

static inline size_t align256(size_t x) { return (x + 255) & ~(size_t)255; }

extern "C" void kernel_launch(void* const* d_in, const int* in_sizes, int n_in,
                              void* d_out, int out_size, void* d_ws, size_t ws_size,
                              hipStream_t stream)
{
    const float* x   = (const float*)d_in[0];
    const int*   ei  = (const int*)d_in[1];
    const float* W1  = (const float*)d_in[2];
    const float* b1  = (const float*)d_in[3];
    const float* W2  = (const float*)d_in[4];
    const float* b2  = (const float*)d_in[5];
    float* out = (float*)d_out;

    const int n_nodes = in_sizes[0] / (B_DIM * C_DIM);
    const int n_edges = in_sizes[1] / 2;
    const int M = B_DIM * n_nodes;
    const size_t elems = (size_t)M * C_DIM;

    const int* src = ei;
    const int* dst = ei + n_edges;
    const int NB = (n_nodes + 255) / 256;

    // ws layout (fast path): bufA (x_bf16 / h1_bf16), bufB (agg), CSR arrays
    size_t off = 0;
    size_t o_bufA    = off; off = align256(off + elems * sizeof(u16));
    size_t o_bufB    = off; off = align256(off + elems * sizeof(u16));
    size_t o_counts  = off; off = align256(off + (size_t)n_nodes * sizeof(int));
    size_t o_offsets = off; off = align256(off + (size_t)n_nodes * sizeof(int));
    size_t o_cursor  = off; off = align256(off + (size_t)n_nodes * sizeof(int));
    size_t o_part    = off; off = align256(off + 256 * sizeof(int));
    size_t o_elist   = off; off = align256(off + (size_t)n_edges * sizeof(u16));
    const size_t need = off;

    const bool fast = (ws_size >= need) && (n_nodes <= 65535) && (NB <= 256) &&
                      ((elems & 7) == 0) && ((n_nodes & 3) == 0);

    dim3 blk(256);

    if (fast) {
        char* ws = (char*)d_ws;
        u16* bufA    = (u16*)(ws + o_bufA);
        u16* bufB    = (u16*)(ws + o_bufB);
        int* counts  = (int*)(ws + o_counts);
        int* offsets = (int*)(ws + o_offsets);
        int* cursor  = (int*)(ws + o_cursor);
        int* partials= (int*)(ws + o_part);
        u16* elist   = (u16*)(ws + o_elist);

        const int cvt_blocks  = (n_nodes * 32 + 255) / 256;
        const int hist_blocks = (n_edges + 255) / 256;
        dim3 grid_pre((unsigned)(cvt_blocks + hist_blocks));
        dim3 grid_e((unsigned)hist_blocks);
        dim3 grid_n((unsigned)NB);
        dim3 grid_g(2048);
        dim3 grid_m(2048);

        hipMemsetAsync(counts, 0, (size_t)n_nodes * sizeof(int), stream);
        k_pre<<<grid_pre, blk, 0, stream>>>(x, bufA, n_nodes, dst, counts,
                                            n_edges, cvt_blocks);
        k_part<<<grid_n, blk, 0, stream>>>(counts, partials, n_nodes);
        k_scan1<<<1, blk, 0, stream>>>(partials, NB);
        k_final<<<grid_n, blk, 0, stream>>>(counts, partials, offsets, cursor, n_nodes);
        k_fill<<<grid_e, blk, 0, stream>>>(src, dst, cursor, elist, n_edges);

        // layer 1
        k_gather<<<grid_g, blk, 0, stream>>>(bufA, elist, offsets, bufB,
                                             n_nodes, n_edges);
        k_mm_mfma<<<grid_m, blk, 0, stream>>>(bufB, W1, b1, nullptr, bufA, n_nodes);
        // layer 2
        k_gather<<<grid_g, blk, 0, stream>>>(bufA, elist, offsets, bufB,
                                             n_nodes, n_edges);
        k_mm_mfma<<<grid_m, blk, 0, stream>>>(bufB, W2, b2, out, nullptr, n_nodes);
    } else {
        // fallback: atomic path
        float* agg = (float*)d_ws;
        const size_t h_bytes = elems * sizeof(float);
        dim3 grid_sc((unsigned)(((long long)n_edges * 64 + 255) / 256));
        dim3 grid_mm((unsigned)((M + 3) / 4));

        hipMemsetAsync(agg, 0, h_bytes, stream);
        gin_scatter<<<grid_sc, blk, 0, stream>>>(x, src, dst, agg, n_edges, n_nodes);
        gin_mm<<<grid_mm, blk, 0, stream>>>(x, agg, W1, b1, out, M);

        hipMemsetAsync(agg, 0, h_bytes, stream);
        gin_scatter<<<grid_sc, blk, 0, stream>>>(out, src, dst, agg, n_edges, n_nodes);
        gin_mm<<<grid_mm, blk, 0, stream>>>(out, agg, W2, b2, out, M);
    }
}